// Round 1
// baseline (3139.935 us; speedup 1.0000x reference)
//
#include <hip/hip_runtime.h>
#include <math.h>

#define BGRAPH 128
#define DIM 64
#define M_FINAL (128*89)   // 11392 final rows

// NS = [706, 353, 177, 89]
__constant__ int d_dummy; // unused

static inline int cdiv(int a, int b) { return (a + b - 1) / b; }

__device__ inline unsigned enc_f(float f) {
    unsigned u = __float_as_uint(f);
    return (u & 0x80000000u) ? ~u : (u | 0x80000000u);
}
__device__ inline float dec_f(unsigned u) {
    return (u & 0x80000000u) ? __uint_as_float(u & 0x7fffffffu)
                             : __uint_as_float(~u);
}

__device__ inline float wave_red_sum(float v) {
    for (int off = 32; off > 0; off >>= 1) v += __shfl_down(v, off, 64);
    return v;
}

// hp[r][d] = sum_f h[r][f] * W[f][d]
__global__ void proj_kernel(const float* __restrict__ h, const float* __restrict__ W,
                            float* __restrict__ hp, int n_rows, int in_dim) {
    int idx = blockIdx.x * blockDim.x + threadIdx.x;
    if (idx >= n_rows * DIM) return;
    int r = idx >> 6, d = idx & 63;
    const float* hr = h + (size_t)r * in_dim;
    float acc = 0.f;
    for (int f = 0; f < in_dim; ++f) acc += hr[f] * W[f * DIM + d];
    hp[idx] = acc;
}

// per-row dots with attention vectors
__global__ void sdots_kernel(const float* __restrict__ hp, const float* __restrict__ asrc,
                             const float* __restrict__ adst,
                             float* __restrict__ s_src, float* __restrict__ s_dst, int n_rows) {
    int r = blockIdx.x;
    int d = threadIdx.x;
    float v = hp[r * DIM + d];
    float a = v * asrc[d];
    float b = v * adst[d];
    for (int off = 32; off > 0; off >>= 1) {
        a += __shfl_down(a, off, 64);
        b += __shfl_down(b, off, 64);
    }
    if (d == 0) { s_src[r] = a; s_dst[r] = b; }
}

__global__ void init_kernel(unsigned* __restrict__ m_enc, float* __restrict__ z,
                            float* __restrict__ gat, const float* __restrict__ bias, int n_rows) {
    int idx = blockIdx.x * blockDim.x + threadIdx.x;
    int total = n_rows * DIM;
    if (idx < total) gat[idx] = bias[idx & 63];
    if (idx < n_rows) { m_enc[idx] = enc_f(-1e30f); z[idx] = 0.f; }
}

__global__ void edge_max_kernel(const int* __restrict__ src, const int* __restrict__ dst,
                                const float* __restrict__ s_src, const float* __restrict__ s_dst,
                                float* __restrict__ attn, unsigned* __restrict__ m_enc, int E) {
    int e = blockIdx.x * blockDim.x + threadIdx.x;
    if (e >= E) return;
    float l = s_src[src[e]] + s_dst[dst[e]];
    l = (l >= 0.f) ? l : 0.2f * l;   // leaky_relu 0.2
    attn[e] = l;
    atomicMax(m_enc + dst[e], enc_f(l));
}

__global__ void edge_exp_kernel(const int* __restrict__ dst, float* __restrict__ attn,
                                const unsigned* __restrict__ m_enc, float* __restrict__ z, int E) {
    int e = blockIdx.x * blockDim.x + threadIdx.x;
    if (e >= E) return;
    int dt = dst[e];
    float p = expf(attn[e] - dec_f(m_enc[dt]));
    attn[e] = p;
    atomicAdd(z + dt, p);
}

__global__ void edge_agg_kernel(const int* __restrict__ src, const int* __restrict__ dst,
                                const float* __restrict__ attn, const float* __restrict__ z,
                                const float* __restrict__ hp, float* __restrict__ gat, int E) {
    int idx = blockIdx.x * blockDim.x + threadIdx.x;
    if (idx >= E * DIM) return;
    int e = idx >> 6, d = idx & 63;
    int s = src[e], dt = dst[e];
    float coef = attn[e] / z[dt];
    atomicAdd(gat + dt * DIM + d, coef * hp[s * DIM + d]);
}

// relu + pairwise max-pool (cluster = k//2 per graph)
__global__ void pool_kernel(const float* __restrict__ gat, float* __restrict__ outp,
                            int nper_in, int nper_out, int n_out_rows) {
    int idx = blockIdx.x * blockDim.x + threadIdx.x;
    if (idx >= n_out_rows * DIM) return;
    int r = idx >> 6, d = idx & 63;
    int b = r / nper_out, cc = r - b * nper_out;
    int r0 = b * nper_in + 2 * cc;
    float v = gat[r0 * DIM + d];
    if (2 * cc + 1 < nper_in) v = fmaxf(v, gat[(r0 + 1) * DIM + d]);
    outp[idx] = fmaxf(v, 0.f);
}

__global__ void zero_kernel(float* __restrict__ p, int n) {
    int i = blockIdx.x * blockDim.x + threadIdx.x;
    if (i < n) p[i] = 0.f;
}

__global__ void bn_stats_kernel(const float* __restrict__ x, double* __restrict__ dstats, int n_rows) {
    int t = threadIdx.x;                  // 256
    int d = t & 63;
    int rstart = blockIdx.x * 4 + (t >> 6);
    int rstride = gridDim.x * 4;
    double s = 0.0, s2 = 0.0;
    for (int r = rstart; r < n_rows; r += rstride) {
        float v = x[r * DIM + d];
        s += v; s2 += (double)v * v;
    }
    atomicAdd(dstats + d, s);
    atomicAdd(dstats + 64 + d, s2);
}

__global__ void bn_finalize_kernel(const double* __restrict__ dstats, float* __restrict__ musig, int n_rows) {
    int d = threadIdx.x;                  // 64
    double mu = dstats[d] / n_rows;
    double var = dstats[64 + d] / n_rows - mu * mu;
    musig[d] = (float)mu;
    musig[64 + d] = rsqrtf((float)var + 1e-5f);
}

__global__ void bn_apply_kernel(const float* __restrict__ x, const float* __restrict__ musig,
                                float* __restrict__ outp, int n_rows) {
    int idx = blockIdx.x * blockDim.x + threadIdx.x;
    if (idx >= n_rows * DIM) return;
    int d = idx & 63;
    outp[idx] = (x[idx] - musig[d]) * musig[64 + d];
}

// Bm[m][v] = dot(ALL[v][m], w_attn)
__global__ void bm_kernel(const float* __restrict__ ALL, const float* __restrict__ w_attn,
                          float* __restrict__ Bm) {
    int m = blockIdx.x;
    int d = threadIdx.x;
    float wa = w_attn[d];
    for (int v = 0; v < 4; ++v) {
        float p = ALL[((size_t)v * M_FINAL + m) * DIM + d] * wa;
        for (int off = 32; off > 0; off >>= 1) p += __shfl_down(p, off, 64);
        if (d == 0) Bm[m * 4 + v] = p;
    }
}

// S[u][v] = sum_m Bm[m][u]*Bm[m][v]
__global__ void s_reduce_kernel(const float* __restrict__ Bm, float* __restrict__ S) {
    __shared__ float acc[16];
    int t = threadIdx.x;
    if (t < 16) acc[t] = 0.f;
    __syncthreads();
    float loc[16];
    for (int k = 0; k < 16; ++k) loc[k] = 0.f;
    for (int m = blockIdx.x * blockDim.x + t; m < M_FINAL; m += gridDim.x * blockDim.x) {
        float4 bv = ((const float4*)Bm)[m];
        float bb[4] = {bv.x, bv.y, bv.z, bv.w};
        for (int u = 0; u < 4; ++u)
            for (int v = 0; v < 4; ++v)
                loc[u * 4 + v] += bb[u] * bb[v];
    }
    for (int k = 0; k < 16; ++k) atomicAdd(&acc[k], loc[k]);
    __syncthreads();
    if (t < 16) atomicAdd(&S[t], acc[t]);
}

// strided column mean numerator: cm[t] += sum over ALL flat idx with idx%256==t
__global__ void cm_kernel(const float* __restrict__ ALL, float* __restrict__ cm) {
    int t = threadIdx.x;                  // 256
    const int total = 4 * M_FINAL * DIM;
    float local = 0.f;
    for (int idx = blockIdx.x * 256 + t; idx < total; idx += gridDim.x * 256)
        local += ALL[idx];
    atomicAdd(cm + t, local);
}

__global__ void fuse_small_kernel(const float* __restrict__ S, const float* __restrict__ cm,
                                  const float* __restrict__ w_lin0, const float* __restrict__ b_lin0,
                                  float* __restrict__ cvec) {
    if (threadIdx.x != 0 || blockIdx.x != 0) return;
    float cn[4];
    for (int v = 0; v < 4; ++v) cn[v] = sqrtf(S[v * 4 + v]);
    float A[16];
    for (int u = 0; u < 4; ++u) {
        float row[4]; float mx = -1e30f;
        for (int v = 0; v < 4; ++v) {
            float g = S[u * 4 + v] / (cn[u] * cn[v]);
            g = (g >= 0.f) ? g : 0.1f * g;       // leaky_relu 0.1
            row[v] = g; mx = fmaxf(mx, g);
        }
        float sum = 0.f;
        for (int v = 0; v < 4; ++v) { row[v] = expf(row[v] - mx); sum += row[v]; }
        for (int v = 0; v < 4; ++v) A[u * 4 + v] = row[v] / sum;
    }
    float e4[4];
    for (int v = 0; v < 4; ++v) {
        float a = b_lin0[v];
        for (int c = 0; c < 256; ++c) a += (cm[c] / (float)M_FINAL) * w_lin0[c * 4 + v];
        e4[v] = a;
    }
    float mx = fmaxf(fmaxf(e4[0], e4[1]), fmaxf(e4[2], e4[3]));
    float sum = 0.f, w[4];
    for (int v = 0; v < 4; ++v) { w[v] = expf(e4[v] - mx); sum += w[v]; }
    for (int v = 0; v < 4; ++v) w[v] /= sum;
    for (int k = 0; k < 4; ++k) {
        float c = 0.f;
        for (int v = 0; v < 4; ++v) c += A[k * 4 + v] * w[v];
        cvec[k] = c;
    }
}

__global__ void combine_kernel(const float* __restrict__ ALL, const float* __restrict__ cvec,
                               float* __restrict__ r) {
    int idx = blockIdx.x * blockDim.x + threadIdx.x;
    if (idx >= M_FINAL * DIM) return;
    float acc = 0.f;
    for (int k = 0; k < 4; ++k) acc += cvec[k] * ALL[k * M_FINAL * DIM + idx];
    r[idx] = acc;
}

// out = (selu?)(in @ W)   W is 64x64 row-major
__global__ void linear_kernel(const float* __restrict__ in, const float* __restrict__ W,
                              float* __restrict__ outp, int n_rows, int do_selu) {
    __shared__ float Wl[DIM * DIM];
    int t = threadIdx.x;   // 256
    for (int k = t; k < DIM * DIM; k += 256) Wl[k] = W[k];
    __syncthreads();
    int idx = blockIdx.x * 256 + t;
    if (idx >= n_rows * DIM) return;
    int r = idx >> 6, d = idx & 63;
    const float* ir = in + r * DIM;
    float acc = 0.f;
    for (int i = 0; i < DIM; ++i) acc += ir[i] * Wl[i * DIM + d];
    if (do_selu) {
        const float scale = 1.0507009873554805f;
        const float alpha = 1.6732632423543772f;
        acc = (acc > 0.f) ? scale * acc : scale * alpha * expm1f(acc);
    }
    outp[idx] = acc;
}

extern "C" void kernel_launch(void* const* d_in, const int* in_sizes, int n_in,
                              void* d_out, int out_size, void* d_ws, size_t ws_size,
                              hipStream_t stream) {
    static const int NS[4] = {706, 353, 177, 89};
    const float* x = (const float*)d_in[15];

    float* ws = (float*)d_ws;
    size_t off = 0;
    float*    hp    = ws + off; off += (size_t)BGRAPH * 706 * DIM;   // 5,783,552
    float*    gat   = ws + off; off += (size_t)BGRAPH * 706 * DIM;   // 5,783,552
    float*    hbuf  = ws + off; off += (size_t)BGRAPH * 353 * DIM;   // 2,891,776
    float*    s_src = ws + off; off += BGRAPH * 706;
    float*    s_dst = ws + off; off += BGRAPH * 706;
    unsigned* m_enc = (unsigned*)(ws + off); off += BGRAPH * 706;
    float*    z     = ws + off; off += BGRAPH * 706;
    float*    attn  = ws + off; off += 1100000;
    float*    ALLb  = ws + off; off += (size_t)4 * M_FINAL * DIM;    // 2,916,352
    float*    small = ws + off;
    float*  cm    = small;            // 256
    float*  S     = small + 256;      // 16
    float*  cvec  = small + 272;      // 4
    float*  musig = small + 276;      // 128
    double* dstats = (double*)(small + 404);  // 128 doubles = 256 float slots

    // ---- per-view GAT stack ----
    for (int j = 0; j < 4; ++j) {
        const float* h = x;
        int in_dim = 3;
        for (int i = 0; i < 3; ++i) {
            int nper_in = NS[i], nper_out = NS[i + 1];
            int n_in_rows = BGRAPH * nper_in, n_out_rows = BGRAPH * nper_out;
            const int* e = (const int*)d_in[j * 3 + i];
            int E = in_sizes[j * 3 + i] / 2;
            const float* W  = (const float*)d_in[16 + 4 * i];
            const float* as = (const float*)d_in[17 + 4 * i];
            const float* ad = (const float*)d_in[18 + 4 * i];
            const float* bb = (const float*)d_in[19 + 4 * i];

            proj_kernel<<<cdiv(n_in_rows * DIM, 256), 256, 0, stream>>>(h, W, hp, n_in_rows, in_dim);
            sdots_kernel<<<n_in_rows, 64, 0, stream>>>(hp, as, ad, s_src, s_dst, n_in_rows);
            init_kernel<<<cdiv(n_in_rows * DIM, 256), 256, 0, stream>>>(m_enc, z, gat, bb, n_in_rows);
            edge_max_kernel<<<cdiv(E, 256), 256, 0, stream>>>(e, e + E, s_src, s_dst, attn, m_enc, E);
            edge_exp_kernel<<<cdiv(E, 256), 256, 0, stream>>>(e + E, attn, m_enc, z, E);
            edge_agg_kernel<<<cdiv(E * DIM, 256), 256, 0, stream>>>(e, e + E, attn, z, hp, gat, E);

            float* P = (i == 2) ? (ALLb + (size_t)j * M_FINAL * DIM) : hbuf;
            pool_kernel<<<cdiv(n_out_rows * DIM, 256), 256, 0, stream>>>(gat, P, nper_in, nper_out, n_out_rows);
            zero_kernel<<<1, 256, 0, stream>>>(small + 404, 256);
            bn_stats_kernel<<<128, 256, 0, stream>>>(P, dstats, n_out_rows);
            bn_finalize_kernel<<<1, 64, 0, stream>>>(dstats, musig, n_out_rows);
            bn_apply_kernel<<<cdiv(n_out_rows * DIM, 256), 256, 0, stream>>>(P, musig, P, n_out_rows);
            h = P; in_dim = DIM;
        }
    }

    // ---- fusion head ----
    const float* w_attn = (const float*)d_in[28];
    const float* w_lin0 = (const float*)d_in[29];
    const float* b_lin0 = (const float*)d_in[30];
    const float* w_link0 = (const float*)d_in[31];
    const float* w_linkl = (const float*)d_in[32];
    const float* w_link_ = (const float*)d_in[33];

    float* Bm = hbuf;     // reuse (needs M_FINAL*4)
    float* r1 = hp;       // reuse
    float* r2 = gat;      // reuse

    zero_kernel<<<cdiv(272, 256), 256, 0, stream>>>(small, 272);  // cm + S
    bm_kernel<<<M_FINAL, 64, 0, stream>>>(ALLb, w_attn, Bm);
    s_reduce_kernel<<<64, 256, 0, stream>>>(Bm, S);
    cm_kernel<<<512, 256, 0, stream>>>(ALLb, cm);
    fuse_small_kernel<<<1, 64, 0, stream>>>(S, cm, w_lin0, b_lin0, cvec);
    combine_kernel<<<cdiv(M_FINAL * DIM, 256), 256, 0, stream>>>(ALLb, cvec, r1);
    linear_kernel<<<cdiv(M_FINAL * DIM, 256), 256, 0, stream>>>(r1, w_link0, r2, M_FINAL, 1);
    linear_kernel<<<cdiv(M_FINAL * DIM, 256), 256, 0, stream>>>(r2, w_linkl, r1, M_FINAL, 1);
    linear_kernel<<<cdiv(M_FINAL * DIM, 256), 256, 0, stream>>>(r1, w_link_, (float*)d_out, M_FINAL, 0);
}

// Round 2
// 1857.609 us; speedup vs baseline: 1.6903x; 1.6903x over previous
//
#include <hip/hip_runtime.h>
#include <math.h>

#define BGRAPH 128
#define DIM 64
#define M_FINAL (128*89)   // 11392 final rows

static inline int cdiv(int a, int b) { return (a + b - 1) / b; }

// ---------------- CSR build (graph-0 only; all 128 graphs share structure) ----

__global__ void zero_int_kernel(int* __restrict__ p, int n) {
    int i = blockIdx.x * blockDim.x + threadIdx.x;
    if (i < n) p[i] = 0;
}

__global__ void hist_kernel(const int* __restrict__ dst0, int* __restrict__ cnt, int ne) {
    int k = blockIdx.x * blockDim.x + threadIdx.x;
    if (k < ne) atomicAdd(cnt + dst0[k], 1);
}

// single block, 1024 threads; n <= 706
__global__ void scan_kernel(const int* __restrict__ cnt, int* __restrict__ rowptr,
                            int* __restrict__ cursor, int n) {
    __shared__ int s[1024];
    int t = threadIdx.x;
    int v = (t < n) ? cnt[t] : 0;
    s[t] = v;
    __syncthreads();
    for (int off = 1; off < 1024; off <<= 1) {
        int add = (t >= off) ? s[t - off] : 0;
        __syncthreads();
        s[t] += add;
        __syncthreads();
    }
    if (t < n) {
        int excl = s[t] - v;
        rowptr[t] = excl;
        cursor[t] = excl;
    }
    if (t == n - 1) rowptr[n] = s[t];
}

__global__ void scatter_kernel(const int* __restrict__ src0, const int* __restrict__ dst0,
                               int* __restrict__ cursor, int* __restrict__ colsrc, int ne) {
    int k = blockIdx.x * blockDim.x + threadIdx.x;
    if (k >= ne) return;
    int pos = atomicAdd(cursor + dst0[k], 1);
    colsrc[pos] = src0[k];
}

// ---------------- fused projection + attention dots (+ optional input BN) ----
// block 256 = 4 waves; each wave handles one row. lane = output dim.
__global__ void projdots_kernel(const float* __restrict__ h, const float* __restrict__ W,
                                const float* __restrict__ musig, int use_bn,
                                const float* __restrict__ asrc, const float* __restrict__ adst,
                                float* __restrict__ hp, float* __restrict__ s_src,
                                float* __restrict__ s_dst, int n_rows, int in_dim) {
    int wave = threadIdx.x >> 6;
    int lane = threadIdx.x & 63;
    int r = blockIdx.x * 4 + wave;
    if (r >= n_rows) return;
    // lane loads its own input element (coalesced), normalized if requested
    float hv = 0.f;
    if (lane < in_dim) {
        hv = h[(size_t)r * in_dim + lane];
        if (use_bn) hv = (hv - musig[lane]) * musig[64 + lane];
    }
    float acc = 0.f;
    for (int f = 0; f < in_dim; ++f) {
        float hf = __shfl(hv, f, 64);
        acc += hf * W[f * DIM + lane];
    }
    hp[(size_t)r * DIM + lane] = acc;
    float a = acc * asrc[lane];
    float b = acc * adst[lane];
    for (int off = 32; off > 0; off >>= 1) {
        a += __shfl_down(a, off, 64);
        b += __shfl_down(b, off, 64);
    }
    if (lane == 0) { s_src[r] = a; s_dst[r] = b; }
}

// ---------------- GAT per-destination softmax + aggregate (no atomics) ------
// one wave per destination row; CSR holds graph-local src indices.
__global__ void gat_dst_kernel(const int* __restrict__ rowptr, const int* __restrict__ colsrc,
                               const float* __restrict__ s_src, const float* __restrict__ s_dst,
                               const float* __restrict__ hp, const float* __restrict__ bias,
                               float* __restrict__ outp, int nper, int n_rows) {
    int wave = threadIdx.x >> 6;
    int lane = threadIdx.x & 63;
    int r = blockIdx.x * 4 + wave;
    if (r >= n_rows) return;
    int b = r / nper;
    int local = r - b * nper;
    int rbase = b * nper;
    int start = rowptr[local];
    int deg = rowptr[local + 1] - start;
    float sd = s_dst[r];

    // pass A: max logit
    float m = -1e30f;
    for (int base = 0; base < deg; base += 64) {
        int i = base + lane;
        float l = -1e30f;
        if (i < deg) {
            int sl = colsrc[start + i];
            float v = s_src[rbase + sl] + sd;
            l = (v >= 0.f) ? v : 0.2f * v;
        }
        m = fmaxf(m, l);
    }
    for (int off = 1; off < 64; off <<= 1) m = fmaxf(m, __shfl_xor(m, off, 64));

    // pass B: unnormalized weights + aggregate
    float zloc = 0.f, acc = 0.f;
    for (int base = 0; base < deg; base += 64) {
        int i = base + lane;
        int sl = 0; float p = 0.f;
        if (i < deg) {
            sl = colsrc[start + i];
            float v = s_src[rbase + sl] + sd;
            v = (v >= 0.f) ? v : 0.2f * v;
            p = expf(v - m);
        }
        zloc += p;
        int cnt = min(64, deg - base);
        for (int k = 0; k < cnt; ++k) {
            int slk = __shfl(sl, k, 64);
            float pk = __shfl(p, k, 64);
            acc += pk * hp[(size_t)(rbase + slk) * DIM + lane];
        }
    }
    for (int off = 1; off < 64; off <<= 1) zloc += __shfl_xor(zloc, off, 64);
    outp[(size_t)r * DIM + lane] = acc / zloc + bias[lane];
}

// relu + pairwise max-pool (cluster = k//2 per graph)
__global__ void pool_kernel(const float* __restrict__ gat, float* __restrict__ outp,
                            int nper_in, int nper_out, int n_out_rows) {
    int idx = blockIdx.x * blockDim.x + threadIdx.x;
    if (idx >= n_out_rows * DIM) return;
    int r = idx >> 6, d = idx & 63;
    int b = r / nper_out, cc = r - b * nper_out;
    int r0 = b * nper_in + 2 * cc;
    float v = gat[r0 * DIM + d];
    if (2 * cc + 1 < nper_in) v = fmaxf(v, gat[(r0 + 1) * DIM + d]);
    outp[idx] = fmaxf(v, 0.f);
}

__global__ void zero_kernel(float* __restrict__ p, int n) {
    int i = blockIdx.x * blockDim.x + threadIdx.x;
    if (i < n) p[i] = 0.f;
}

__global__ void bn_stats_kernel(const float* __restrict__ x, double* __restrict__ dstats, int n_rows) {
    int t = threadIdx.x;                  // 256
    int d = t & 63;
    int rstart = blockIdx.x * 4 + (t >> 6);
    int rstride = gridDim.x * 4;
    double s = 0.0, s2 = 0.0;
    for (int r = rstart; r < n_rows; r += rstride) {
        float v = x[r * DIM + d];
        s += v; s2 += (double)v * v;
    }
    atomicAdd(dstats + d, s);
    atomicAdd(dstats + 64 + d, s2);
}

__global__ void bn_finalize_kernel(const double* __restrict__ dstats, float* __restrict__ musig, int n_rows) {
    int d = threadIdx.x;                  // 64
    double mu = dstats[d] / n_rows;
    double var = dstats[64 + d] / n_rows - mu * mu;
    musig[d] = (float)mu;
    musig[64 + d] = rsqrtf((float)var + 1e-5f);
}

__global__ void bn_apply_kernel(const float* __restrict__ x, const float* __restrict__ musig,
                                float* __restrict__ outp, int n_rows) {
    int idx = blockIdx.x * blockDim.x + threadIdx.x;
    if (idx >= n_rows * DIM) return;
    int d = idx & 63;
    outp[idx] = (x[idx] - musig[d]) * musig[64 + d];
}

// ---------------- fusion head ----------------

__global__ void bm_kernel(const float* __restrict__ ALL, const float* __restrict__ w_attn,
                          float* __restrict__ Bm) {
    int m = blockIdx.x;
    int d = threadIdx.x;
    float wa = w_attn[d];
    for (int v = 0; v < 4; ++v) {
        float p = ALL[((size_t)v * M_FINAL + m) * DIM + d] * wa;
        for (int off = 32; off > 0; off >>= 1) p += __shfl_down(p, off, 64);
        if (d == 0) Bm[m * 4 + v] = p;
    }
}

__global__ void s_reduce_kernel(const float* __restrict__ Bm, float* __restrict__ S) {
    __shared__ float acc[16];
    int t = threadIdx.x;
    if (t < 16) acc[t] = 0.f;
    __syncthreads();
    float loc[16];
    for (int k = 0; k < 16; ++k) loc[k] = 0.f;
    for (int m = blockIdx.x * blockDim.x + t; m < M_FINAL; m += gridDim.x * blockDim.x) {
        float4 bv = ((const float4*)Bm)[m];
        float bb[4] = {bv.x, bv.y, bv.z, bv.w};
        for (int u = 0; u < 4; ++u)
            for (int v = 0; v < 4; ++v)
                loc[u * 4 + v] += bb[u] * bb[v];
    }
    for (int k = 0; k < 16; ++k) atomicAdd(&acc[k], loc[k]);
    __syncthreads();
    if (t < 16) atomicAdd(&S[t], acc[t]);
}

__global__ void cm_kernel(const float* __restrict__ ALL, float* __restrict__ cm) {
    int t = threadIdx.x;                  // 256
    const int total = 4 * M_FINAL * DIM;
    float local = 0.f;
    for (int idx = blockIdx.x * 256 + t; idx < total; idx += gridDim.x * 256)
        local += ALL[idx];
    atomicAdd(cm + t, local);
}

__global__ void fuse_small_kernel(const float* __restrict__ S, const float* __restrict__ cm,
                                  const float* __restrict__ w_lin0, const float* __restrict__ b_lin0,
                                  float* __restrict__ cvec) {
    if (threadIdx.x != 0 || blockIdx.x != 0) return;
    float cn[4];
    for (int v = 0; v < 4; ++v) cn[v] = sqrtf(S[v * 4 + v]);
    float A[16];
    for (int u = 0; u < 4; ++u) {
        float row[4]; float mx = -1e30f;
        for (int v = 0; v < 4; ++v) {
            float g = S[u * 4 + v] / (cn[u] * cn[v]);
            g = (g >= 0.f) ? g : 0.1f * g;       // leaky_relu 0.1
            row[v] = g; mx = fmaxf(mx, g);
        }
        float sum = 0.f;
        for (int v = 0; v < 4; ++v) { row[v] = expf(row[v] - mx); sum += row[v]; }
        for (int v = 0; v < 4; ++v) A[u * 4 + v] = row[v] / sum;
    }
    float e4[4];
    for (int v = 0; v < 4; ++v) {
        float a = b_lin0[v];
        for (int c = 0; c < 256; ++c) a += (cm[c] / (float)M_FINAL) * w_lin0[c * 4 + v];
        e4[v] = a;
    }
    float mx = fmaxf(fmaxf(e4[0], e4[1]), fmaxf(e4[2], e4[3]));
    float sum = 0.f, w[4];
    for (int v = 0; v < 4; ++v) { w[v] = expf(e4[v] - mx); sum += w[v]; }
    for (int v = 0; v < 4; ++v) w[v] /= sum;
    for (int k = 0; k < 4; ++k) {
        float c = 0.f;
        for (int v = 0; v < 4; ++v) c += A[k * 4 + v] * w[v];
        cvec[k] = c;
    }
}

__global__ void combine_kernel(const float* __restrict__ ALL, const float* __restrict__ cvec,
                               float* __restrict__ r) {
    int idx = blockIdx.x * blockDim.x + threadIdx.x;
    if (idx >= M_FINAL * DIM) return;
    float acc = 0.f;
    for (int k = 0; k < 4; ++k) acc += cvec[k] * ALL[k * M_FINAL * DIM + idx];
    r[idx] = acc;
}

__global__ void linear_kernel(const float* __restrict__ in, const float* __restrict__ W,
                              float* __restrict__ outp, int n_rows, int do_selu) {
    __shared__ float Wl[DIM * DIM];
    int t = threadIdx.x;   // 256
    for (int k = t; k < DIM * DIM; k += 256) Wl[k] = W[k];
    __syncthreads();
    int idx = blockIdx.x * 256 + t;
    if (idx >= n_rows * DIM) return;
    int r = idx >> 6, d = idx & 63;
    const float* ir = in + r * DIM;
    float acc = 0.f;
    for (int i = 0; i < DIM; ++i) acc += ir[i] * Wl[i * DIM + d];
    if (do_selu) {
        const float scale = 1.0507009873554805f;
        const float alpha = 1.6732632423543772f;
        acc = (acc > 0.f) ? scale * acc : scale * alpha * expm1f(acc);
    }
    outp[idx] = acc;
}

extern "C" void kernel_launch(void* const* d_in, const int* in_sizes, int n_in,
                              void* d_out, int out_size, void* d_ws, size_t ws_size,
                              hipStream_t stream) {
    static const int NS[4] = {706, 353, 177, 89};
    const float* x = (const float*)d_in[15];

    float* ws = (float*)d_ws;
    size_t off = 0;
    float*    hp    = ws + off; off += (size_t)BGRAPH * 706 * DIM;   // 5,783,552
    float*    gat   = ws + off; off += (size_t)BGRAPH * 706 * DIM;   // 5,783,552
    float*    hbuf  = ws + off; off += (size_t)BGRAPH * 353 * DIM;   // 2,891,776
    float*    s_src = ws + off; off += BGRAPH * 706;
    float*    s_dst = ws + off; off += BGRAPH * 706;
    float*    ALLb  = ws + off; off += (size_t)4 * M_FINAL * DIM;    // 2,916,352
    int*      cnt     = (int*)(ws + off); off += 1024;
    int*      rowptr  = (int*)(ws + off); off += 1024;
    int*      cursor  = (int*)(ws + off); off += 1024;
    int*      colsrc  = (int*)(ws + off); off += 8192;
    float*    small = ws + off;
    float*  cm    = small;            // 256
    float*  S     = small + 256;      // 16
    float*  cvec  = small + 272;      // 4
    float*  musig = small + 276;      // 128
    double* dstats = (double*)(small + 404);  // 128 doubles = 256 float slots

    // ---- per-view GAT stack ----
    for (int j = 0; j < 4; ++j) {
        const float* h = x;
        int in_dim = 3;
        for (int i = 0; i < 3; ++i) {
            int nper_in = NS[i], nper_out = NS[i + 1];
            int n_in_rows = BGRAPH * nper_in, n_out_rows = BGRAPH * nper_out;
            const int* e = (const int*)d_in[j * 3 + i];
            int E = in_sizes[j * 3 + i] / 2;
            int ne = E / BGRAPH;                 // graph-0 edge count
            const int* src0 = e;                 // graph-0 src (zero offset)
            const int* dst0 = e + E;             // graph-0 dst
            const float* W  = (const float*)d_in[16 + 4 * i];
            const float* as = (const float*)d_in[17 + 4 * i];
            const float* ad = (const float*)d_in[18 + 4 * i];
            const float* bb = (const float*)d_in[19 + 4 * i];

            // CSR build (graph-local)
            zero_int_kernel<<<cdiv(nper_in, 256), 256, 0, stream>>>(cnt, nper_in);
            hist_kernel<<<cdiv(ne, 256), 256, 0, stream>>>(dst0, cnt, ne);
            scan_kernel<<<1, 1024, 0, stream>>>(cnt, rowptr, cursor, nper_in);
            scatter_kernel<<<cdiv(ne, 256), 256, 0, stream>>>(src0, dst0, cursor, colsrc, ne);

            // projection + attention dots (+ BN of previous layer fused in)
            projdots_kernel<<<cdiv(n_in_rows, 4), 256, 0, stream>>>(
                h, W, musig, (i > 0) ? 1 : 0, as, ad, hp, s_src, s_dst, n_in_rows, in_dim);

            // per-destination softmax + aggregation
            gat_dst_kernel<<<cdiv(n_in_rows, 4), 256, 0, stream>>>(
                rowptr, colsrc, s_src, s_dst, hp, bb, gat, nper_in, n_in_rows);

            float* P = (i == 2) ? (ALLb + (size_t)j * M_FINAL * DIM) : hbuf;
            pool_kernel<<<cdiv(n_out_rows * DIM, 256), 256, 0, stream>>>(gat, P, nper_in, nper_out, n_out_rows);
            zero_kernel<<<1, 256, 0, stream>>>(small + 404, 256);
            bn_stats_kernel<<<128, 256, 0, stream>>>(P, dstats, n_out_rows);
            bn_finalize_kernel<<<1, 64, 0, stream>>>(dstats, musig, n_out_rows);
            if (i == 2) {
                bn_apply_kernel<<<cdiv(n_out_rows * DIM, 256), 256, 0, stream>>>(P, musig, P, n_out_rows);
            }
            h = P; in_dim = DIM;
        }
    }

    // ---- fusion head ----
    const float* w_attn = (const float*)d_in[28];
    const float* w_lin0 = (const float*)d_in[29];
    const float* b_lin0 = (const float*)d_in[30];
    const float* w_link0 = (const float*)d_in[31];
    const float* w_linkl = (const float*)d_in[32];
    const float* w_link_ = (const float*)d_in[33];

    float* Bm = hbuf;     // reuse (needs M_FINAL*4)
    float* r1 = hp;       // reuse
    float* r2 = gat;      // reuse

    zero_kernel<<<cdiv(272, 256), 256, 0, stream>>>(small, 272);  // cm + S
    bm_kernel<<<M_FINAL, 64, 0, stream>>>(ALLb, w_attn, Bm);
    s_reduce_kernel<<<64, 256, 0, stream>>>(Bm, S);
    cm_kernel<<<512, 256, 0, stream>>>(ALLb, cm);
    fuse_small_kernel<<<1, 64, 0, stream>>>(S, cm, w_lin0, b_lin0, cvec);
    combine_kernel<<<cdiv(M_FINAL * DIM, 256), 256, 0, stream>>>(ALLb, cvec, r1);
    linear_kernel<<<cdiv(M_FINAL * DIM, 256), 256, 0, stream>>>(r1, w_link0, r2, M_FINAL, 1);
    linear_kernel<<<cdiv(M_FINAL * DIM, 256), 256, 0, stream>>>(r2, w_linkl, r1, M_FINAL, 1);
    linear_kernel<<<cdiv(M_FINAL * DIM, 256), 256, 0, stream>>>(r1, w_link_, (float*)d_out, M_FINAL, 0);
}

// Round 3
// 1377.352 us; speedup vs baseline: 2.2797x; 1.3487x over previous
//
#include <hip/hip_runtime.h>
#include <math.h>

#define DIM 64
#define M_FINAL (128*89)   // 11392 final rows

static inline int cdiv(int a, int b) { return (a + b - 1) / b; }

struct EdgeSets {
    const int* src[12];
    const int* dst[12];
    int ne[12];
};

struct LayerArgs {
    const float* h[4];        // per-view input rows
    float* out[4];            // per-view pooled output rows
    const int* rowptr[4];
    const int* colsrc[4];
    const float* musig_prev;  // + j*128 ; unused for L==0
    double* dstats;           // + j*128
    const float* W;
    const float* as;
    const float* ad;
    const float* bias;
};

// ---------------- batched CSR build (graph-0 structure shared by all 128) ---

__global__ void zero_kernel(float* __restrict__ p, int n) {
    int i = blockIdx.x * blockDim.x + threadIdx.x;
    if (i < n) p[i] = 0.f;
}

__global__ void hist12_kernel(EdgeSets ES, int* __restrict__ cnt_all) {
    int s = blockIdx.y;
    int k = blockIdx.x * 256 + threadIdx.x;
    if (k < ES.ne[s]) atomicAdd(cnt_all + s * 768 + ES.dst[s][k], 1);
}

__global__ void scan12_kernel(const int* __restrict__ cnt_all, int* __restrict__ rowptr_all,
                              int* __restrict__ cursor_all) {
    __shared__ int sbuf[1024];
    int set = blockIdx.x;
    int lay = set % 3;
    int n = (lay == 0) ? 706 : (lay == 1) ? 353 : 177;
    const int* cnt = cnt_all + set * 768;
    int* rowptr = rowptr_all + set * 768;
    int* cursor = cursor_all + set * 768;
    int t = threadIdx.x;
    int v = (t < n) ? cnt[t] : 0;
    sbuf[t] = v;
    __syncthreads();
    for (int off = 1; off < 1024; off <<= 1) {
        int add = (t >= off) ? sbuf[t - off] : 0;
        __syncthreads();
        sbuf[t] += add;
        __syncthreads();
    }
    if (t < n) { int e = sbuf[t] - v; rowptr[t] = e; cursor[t] = e; }
    if (t == n - 1) rowptr[n] = sbuf[t];
}

__global__ void scatter12_kernel(EdgeSets ES, int* __restrict__ cursor_all,
                                 int* __restrict__ colsrc_all) {
    int s = blockIdx.y;
    int k = blockIdx.x * 256 + threadIdx.x;
    if (k >= ES.ne[s]) return;
    int pos = atomicAdd(cursor_all + s * 768 + ES.dst[s][k], 1);
    colsrc_all[s * 8192 + pos] = ES.src[s][k];
}

// ---------------- fused per-layer mega kernel ------------------------------
// block = (split, view, graph); 256 threads = 4 waves; wave owns output
// clusters c = wave + 4*split + 8*t. Does: [BN] -> s-dots -> GAT softmax ->
// h-space aggregate -> @W + bias -> relu -> pairwise max-pool -> BN stats.
template<int L>
__global__ __launch_bounds__(256)
void layer_kernel(LayerArgs A) {
    constexpr int NPIN  = (L == 0) ? 706 : (L == 1) ? 353 : 177;
    constexpr int NPOUT = NPIN / 2 + (NPIN & 1);   // 353, 177, 89
    __shared__ float sSrc[NPIN];
    __shared__ float sDst[NPIN];
    __shared__ float hL[(L == 0) ? 706 * 3 : ((L == 2) ? 177 * 64 : 1)];
    __shared__ float waL[(L == 0) ? 8 : 128];
    __shared__ double sred[2][4][64];

    const int bid = blockIdx.x;
    const int split = bid >> 9;       // 0/1: cluster-range interleave
    const int jg = bid & 511;
    const int j = jg >> 7;            // view
    const int g = jg & 127;           // graph
    const int tid = threadIdx.x;
    const int wave = tid >> 6;
    const int lane = tid & 63;

    const float* __restrict__ h = A.h[j];
    const int* __restrict__ rowptr = A.rowptr[j];
    const int* __restrict__ colsrc = A.colsrc[j];
    const float* __restrict__ W = A.W;

    float mu = 0.f, rs = 1.f;
    if constexpr (L == 1) {
        mu = A.musig_prev[j * 128 + lane];
        rs = A.musig_prev[j * 128 + 64 + lane];
    }

    if constexpr (L == 0) {
        if (tid < 6) {                    // wa_{src,dst}[f] = sum_d W[f][d]*a[d]
            int f = (tid < 3) ? tid : tid - 3;
            const float* av = (tid < 3) ? A.as : A.ad;
            float acc = 0.f;
            for (int d = 0; d < 64; ++d) acc += W[f * 64 + d] * av[d];
            waL[tid] = acc;
        }
        for (int k = tid; k < 706 * 3; k += 256) hL[k] = h[(size_t)g * 2118 + k];
        __syncthreads();
        for (int r = tid; r < 706; r += 256) {
            float h0 = hL[r * 3], h1 = hL[r * 3 + 1], h2 = hL[r * 3 + 2];
            sSrc[r] = h0 * waL[0] + h1 * waL[1] + h2 * waL[2];
            sDst[r] = h0 * waL[3] + h1 * waL[4] + h2 * waL[5];
        }
        __syncthreads();
    } else {
        for (int f = wave; f < 64; f += 4) {   // wa vectors, wave per f
            float w = W[f * 64 + lane];
            float a = w * A.as[lane];
            float b = w * A.ad[lane];
            for (int off = 32; off > 0; off >>= 1) {
                a += __shfl_down(a, off, 64);
                b += __shfl_down(b, off, 64);
            }
            if (lane == 0) { waL[f] = a; waL[64 + f] = b; }
        }
        if constexpr (L == 2) {               // stage BN'd h into LDS
            for (int k = tid; k < 177 * 64; k += 256) {
                float v = h[(size_t)g * 177 * 64 + k];
                v = (v - A.musig_prev[j * 128 + (k & 63)]) *
                    A.musig_prev[j * 128 + 64 + (k & 63)];
                hL[k] = v;
            }
        }
        __syncthreads();
        for (int r = wave; r < NPIN; r += 4) {   // s-dots
            float v;
            if constexpr (L == 1) v = (h[((size_t)g * NPIN + r) * 64 + lane] - mu) * rs;
            else                  v = hL[r * 64 + lane];
            float a = v * waL[lane];
            float b = v * waL[64 + lane];
            for (int off = 32; off > 0; off >>= 1) {
                a += __shfl_down(a, off, 64);
                b += __shfl_down(b, off, 64);
            }
            if (lane == 0) { sSrc[r] = a; sDst[r] = b; }
        }
        __syncthreads();
    }

    float w0 = 0.f, w1 = 0.f, w2 = 0.f;
    if constexpr (L == 0) { w0 = W[lane]; w1 = W[64 + lane]; w2 = W[128 + lane]; }
    const float b_l = A.bias[lane];
    float* outj = A.out[j];
    double bs = 0.0, bs2 = 0.0;

    for (int c = wave + 4 * split; c < NPOUT; c += 8) {
        float vmax = 0.f;                      // children are relu'd -> >= 0
        for (int ch = 0; ch < 2; ++ch) {
            int child = 2 * c + ch;
            if (child >= NPIN) break;
            int start = rowptr[child];
            int deg = rowptr[child + 1] - start;
            float sd = sDst[child];
            float m = -1e30f;
            for (int k = 0; k < deg; ++k) {
                int sl = colsrc[start + k];
                float v = sSrc[sl] + sd;
                v = (v >= 0.f) ? v : 0.2f * v;
                m = fmaxf(m, v);
            }
            float z = 0.f, acc = 0.f, a0 = 0.f, a1 = 0.f, a2 = 0.f;
            for (int k = 0; k < deg; ++k) {
                int sl = colsrc[start + k];
                float v = sSrc[sl] + sd;
                v = (v >= 0.f) ? v : 0.2f * v;
                float p = __expf(v - m);
                z += p;
                if constexpr (L == 0) {
                    a0 += p * hL[sl * 3];
                    a1 += p * hL[sl * 3 + 1];
                    a2 += p * hL[sl * 3 + 2];
                } else if constexpr (L == 1) {
                    acc += p * ((h[((size_t)g * NPIN + sl) * 64 + lane] - mu) * rs);
                } else {
                    acc += p * hL[sl * 64 + lane];
                }
            }
            float inv = 1.f / z;
            float o;
            if constexpr (L == 0) {
                o = (a0 * w0 + a1 * w1 + a2 * w2) * inv + b_l;
            } else {
                float agg = acc * inv;
                o = b_l;
                #pragma unroll 8
                for (int f = 0; f < 64; ++f)
                    o += __shfl(agg, f, 64) * W[f * 64 + lane];
            }
            vmax = fmaxf(vmax, fmaxf(o, 0.f));
        }
        outj[((size_t)g * NPOUT + c) * 64 + lane] = vmax;
        bs += vmax;
        bs2 += (double)vmax * vmax;
    }
    sred[0][wave][lane] = bs;
    sred[1][wave][lane] = bs2;
    __syncthreads();
    if (wave == 0) {
        double t1 = sred[0][0][lane] + sred[0][1][lane] + sred[0][2][lane] + sred[0][3][lane];
        double t2 = sred[1][0][lane] + sred[1][1][lane] + sred[1][2][lane] + sred[1][3][lane];
        atomicAdd(A.dstats + j * 128 + lane, t1);
        atomicAdd(A.dstats + j * 128 + 64 + lane, t2);
    }
}

__global__ void bn_finalize_kernel(const double* __restrict__ dstats,
                                   float* __restrict__ musig, int n_rows) {
    int jv = blockIdx.x;           // view
    int d = threadIdx.x;           // 64
    double mu = dstats[jv * 128 + d] / n_rows;
    double var = dstats[jv * 128 + 64 + d] / n_rows - mu * mu;
    musig[jv * 128 + d] = (float)mu;
    musig[jv * 128 + 64 + d] = rsqrtf((float)var + 1e-5f);
}

// in-place BN over ALLb (4 views)
__global__ void bn_apply_kernel(float* __restrict__ x, const float* __restrict__ musig) {
    int idx = blockIdx.x * 256 + threadIdx.x;
    if (idx >= 4 * M_FINAL * 64) return;
    int v = idx / (M_FINAL * 64);
    int d = idx & 63;
    x[idx] = (x[idx] - musig[v * 128 + d]) * musig[v * 128 + 64 + d];
}

// ---------------- fusion head ----------------

__global__ void bm_kernel(const float* __restrict__ ALL, const float* __restrict__ w_attn,
                          float* __restrict__ Bm) {
    int m = blockIdx.x;
    int d = threadIdx.x;
    float wa = w_attn[d];
    for (int v = 0; v < 4; ++v) {
        float p = ALL[((size_t)v * M_FINAL + m) * DIM + d] * wa;
        for (int off = 32; off > 0; off >>= 1) p += __shfl_down(p, off, 64);
        if (d == 0) Bm[m * 4 + v] = p;
    }
}

__global__ void s_reduce_kernel(const float* __restrict__ Bm, float* __restrict__ S) {
    __shared__ float acc[16];
    int t = threadIdx.x;
    if (t < 16) acc[t] = 0.f;
    __syncthreads();
    float loc[16];
    for (int k = 0; k < 16; ++k) loc[k] = 0.f;
    for (int m = blockIdx.x * blockDim.x + t; m < M_FINAL; m += gridDim.x * blockDim.x) {
        float4 bv = ((const float4*)Bm)[m];
        float bb[4] = {bv.x, bv.y, bv.z, bv.w};
        for (int u = 0; u < 4; ++u)
            for (int v = 0; v < 4; ++v)
                loc[u * 4 + v] += bb[u] * bb[v];
    }
    for (int k = 0; k < 16; ++k) atomicAdd(&acc[k], loc[k]);
    __syncthreads();
    if (t < 16) atomicAdd(&S[t], acc[t]);
}

__global__ void cm_kernel(const float* __restrict__ ALL, float* __restrict__ cm) {
    int t = threadIdx.x;                  // 256
    const int total = 4 * M_FINAL * DIM;
    float local = 0.f;
    for (int idx = blockIdx.x * 256 + t; idx < total; idx += gridDim.x * 256)
        local += ALL[idx];
    atomicAdd(cm + t, local);
}

__global__ void fuse_small_kernel(const float* __restrict__ S, const float* __restrict__ cm,
                                  const float* __restrict__ w_lin0, const float* __restrict__ b_lin0,
                                  float* __restrict__ cvec) {
    if (threadIdx.x != 0 || blockIdx.x != 0) return;
    float cn[4];
    for (int v = 0; v < 4; ++v) cn[v] = sqrtf(S[v * 4 + v]);
    float A[16];
    for (int u = 0; u < 4; ++u) {
        float row[4]; float mx = -1e30f;
        for (int v = 0; v < 4; ++v) {
            float g = S[u * 4 + v] / (cn[u] * cn[v]);
            g = (g >= 0.f) ? g : 0.1f * g;       // leaky_relu 0.1
            row[v] = g; mx = fmaxf(mx, g);
        }
        float sum = 0.f;
        for (int v = 0; v < 4; ++v) { row[v] = expf(row[v] - mx); sum += row[v]; }
        for (int v = 0; v < 4; ++v) A[u * 4 + v] = row[v] / sum;
    }
    float e4[4];
    for (int v = 0; v < 4; ++v) {
        float a = b_lin0[v];
        for (int c = 0; c < 256; ++c) a += (cm[c] / (float)M_FINAL) * w_lin0[c * 4 + v];
        e4[v] = a;
    }
    float mx = fmaxf(fmaxf(e4[0], e4[1]), fmaxf(e4[2], e4[3]));
    float sum = 0.f, w[4];
    for (int v = 0; v < 4; ++v) { w[v] = expf(e4[v] - mx); sum += w[v]; }
    for (int v = 0; v < 4; ++v) w[v] /= sum;
    for (int k = 0; k < 4; ++k) {
        float c = 0.f;
        for (int v = 0; v < 4; ++v) c += A[k * 4 + v] * w[v];
        cvec[k] = c;
    }
}

__global__ void combine_kernel(const float* __restrict__ ALL, const float* __restrict__ cvec,
                               float* __restrict__ r) {
    int idx = blockIdx.x * blockDim.x + threadIdx.x;
    if (idx >= M_FINAL * DIM) return;
    float acc = 0.f;
    for (int k = 0; k < 4; ++k) acc += cvec[k] * ALL[(size_t)k * M_FINAL * DIM + idx];
    r[idx] = acc;
}

__global__ void linear_kernel(const float* __restrict__ in, const float* __restrict__ W,
                              float* __restrict__ outp, int n_rows, int do_selu) {
    __shared__ float Wl[DIM * DIM];
    int t = threadIdx.x;   // 256
    for (int k = t; k < DIM * DIM; k += 256) Wl[k] = W[k];
    __syncthreads();
    int idx = blockIdx.x * 256 + t;
    if (idx >= n_rows * DIM) return;
    int r = idx >> 6, d = idx & 63;
    const float* ir = in + r * DIM;
    float acc = 0.f;
    for (int i = 0; i < DIM; ++i) acc += ir[i] * Wl[i * DIM + d];
    if (do_selu) {
        const float scale = 1.0507009873554805f;
        const float alpha = 1.6732632423543772f;
        acc = (acc > 0.f) ? scale * acc : scale * alpha * expm1f(acc);
    }
    outp[idx] = acc;
}

extern "C" void kernel_launch(void* const* d_in, const int* in_sizes, int n_in,
                              void* d_out, int out_size, void* d_ws, size_t ws_size,
                              hipStream_t stream) {
    const float* x = (const float*)d_in[15];

    float* ws = (float*)d_ws;
    // workspace layout (float slots)
    double* dstats_all = (double*)ws;                 // [0, 3072) = 1536 doubles
    float*  cm        = ws + 3072;                    // 256
    float*  S         = ws + 3328;                    // 16
    float*  cvec      = ws + 3344;                    // 4
    int*    cnt_all    = (int*)(ws + 3584);           // 12*768
    int*    rowptr_all = (int*)(ws + 12800);          // 12*768
    int*    cursor_all = (int*)(ws + 22016);          // 12*768
    int*    colsrc_all = (int*)(ws + 31232);          // 12*8192
    float*  musig_all  = ws + 129536;                 // 3*4*128
    float*  A_buf      = ws + 131072;                 // 4 * 128*353*64 = 11,567,104
    float*  B_buf      = ws + 131072 + 11567104;      // 4 * 128*177*64 = 5,799,936
    float*  ALLb       = A_buf;                       // aliases A (dead by layer 2)
    const size_t as0 = (size_t)128 * 353 * 64;
    const size_t as1 = (size_t)128 * 177 * 64;

    // edge set table
    EdgeSets ES;
    int maxne = 0;
    for (int s = 0; s < 12; ++s) {
        const int* e = (const int*)d_in[s];
        int E = in_sizes[s] / 2;
        int ne = E / 128;                 // graph-0 edges (shared structure)
        ES.src[s] = e;
        ES.dst[s] = e + E;
        ES.ne[s] = ne;
        if (ne > maxne) maxne = ne;
    }

    // zero: dstats + cm/S + cnt_all  (float slots [0, 12800))
    zero_kernel<<<cdiv(12800, 256), 256, 0, stream>>>(ws, 12800);
    hist12_kernel<<<dim3(cdiv(maxne, 256), 12), 256, 0, stream>>>(ES, cnt_all);
    scan12_kernel<<<12, 1024, 0, stream>>>(cnt_all, rowptr_all, cursor_all);
    scatter12_kernel<<<dim3(cdiv(maxne, 256), 12), 256, 0, stream>>>(ES, cursor_all, colsrc_all);

    // layers
    for (int L = 0; L < 3; ++L) {
        LayerArgs LA;
        for (int j = 0; j < 4; ++j) {
            int s = j * 3 + L;
            LA.rowptr[j] = rowptr_all + s * 768;
            LA.colsrc[j] = colsrc_all + s * 8192;
            if (L == 0) { LA.h[j] = x;              LA.out[j] = A_buf + j * as0; }
            if (L == 1) { LA.h[j] = A_buf + j * as0; LA.out[j] = B_buf + j * as1; }
            if (L == 2) { LA.h[j] = B_buf + j * as1; LA.out[j] = ALLb + (size_t)j * M_FINAL * 64; }
        }
        LA.musig_prev = (L == 0) ? nullptr : (musig_all + (L - 1) * 512);
        LA.dstats = dstats_all + L * 512;
        LA.W    = (const float*)d_in[16 + 4 * L];
        LA.as   = (const float*)d_in[17 + 4 * L];
        LA.ad   = (const float*)d_in[18 + 4 * L];
        LA.bias = (const float*)d_in[19 + 4 * L];
        if (L == 0) layer_kernel<0><<<1024, 256, 0, stream>>>(LA);
        if (L == 1) layer_kernel<1><<<1024, 256, 0, stream>>>(LA);
        if (L == 2) layer_kernel<2><<<1024, 256, 0, stream>>>(LA);
        static const int NPOUT[3] = {353, 177, 89};
        bn_finalize_kernel<<<4, 64, 0, stream>>>(dstats_all + L * 512, musig_all + L * 512,
                                                 128 * NPOUT[L]);
    }
    bn_apply_kernel<<<cdiv(4 * M_FINAL * 64, 256), 256, 0, stream>>>(ALLb, musig_all + 2 * 512);

    // ---- fusion head ----
    const float* w_attn = (const float*)d_in[28];
    const float* w_lin0 = (const float*)d_in[29];
    const float* b_lin0 = (const float*)d_in[30];
    const float* w_link0 = (const float*)d_in[31];
    const float* w_linkl = (const float*)d_in[32];
    const float* w_link_ = (const float*)d_in[33];

    float* r1 = B_buf;                       // reuse (dead after layer 2)
    float* r2 = B_buf + 729088;
    float* Bm = B_buf + 2 * 729088;

    bm_kernel<<<M_FINAL, 64, 0, stream>>>(ALLb, w_attn, Bm);
    s_reduce_kernel<<<64, 256, 0, stream>>>(Bm, S);
    cm_kernel<<<512, 256, 0, stream>>>(ALLb, cm);
    fuse_small_kernel<<<1, 64, 0, stream>>>(S, cm, w_lin0, b_lin0, cvec);
    combine_kernel<<<cdiv(M_FINAL * DIM, 256), 256, 0, stream>>>(ALLb, cvec, r1);
    linear_kernel<<<cdiv(M_FINAL * DIM, 256), 256, 0, stream>>>(r1, w_link0, r2, M_FINAL, 1);
    linear_kernel<<<cdiv(M_FINAL * DIM, 256), 256, 0, stream>>>(r2, w_linkl, r1, M_FINAL, 1);
    linear_kernel<<<cdiv(M_FINAL * DIM, 256), 256, 0, stream>>>(r1, w_link_, (float*)d_out, M_FINAL, 0);
}